// Round 8
// baseline (112.352 us; speedup 1.0000x reference)
//
#include <hip/hip_runtime.h>
#include <math.h>

#define N_SAMPLES 4
#define P_ELEMS   (96*96*96)          // 884736
// minmax geometry: deep loads, pure BW
#define MM_BPS    216
#define MM_T4     1024                // float4 per array per block (4/thread)
// hist geometry: balanced 8 blocks/CU exactly (2048 blocks on 256 CUs)
#define H_BPS     512
#define H_TILE    1728                // P_ELEMS / H_BPS, exact
#define H_T4      (H_TILE/4)          // 432 float4 per array per block
#define WSLICE    (H_TILE/4)          // 432 elements per wave
#define NITER     (WSLICE/16)         // 27 MFMA iterations per wave
#define NCOPY     8                   // replicated global hists (contention / XCD spread)
#define PW_SLOTS  1728                // ws layout constant (matches prior rounds)
// weight = exp(-(xb-k)^2 * 2048/961) = exp2(-((xb-k)*WS)^2), WS = sqrt(2048/961*log2 e)
#define WS        1.75343855f
#define EPSR      1e-10f

typedef __attribute__((ext_vector_type(8)))  short short8;
typedef __attribute__((ext_vector_type(16))) float float16;

// ---------------- dispatch 1: per-block minmax partials + hist zeroing ----------------

__global__ void __launch_bounds__(256)
k_minmax(const float* __restrict__ tar, const float* __restrict__ src,
         float4* __restrict__ pw, float* __restrict__ histall) {
    __shared__ float4 sred[4];
    int n = blockIdx.y, j = blockIdx.x;
    int t = threadIdx.x;
    const float4* t4 = (const float4*)(tar + (size_t)n * P_ELEMS) + (size_t)j * MM_T4;
    const float4* s4 = (const float4*)(src + (size_t)n * P_ELEMS) + (size_t)j * MM_T4;
    float4 a0 = t4[t], a1 = t4[t + 256], a2 = t4[t + 512], a3 = t4[t + 768];
    float4 b0 = s4[t], b1 = s4[t + 256], b2 = s4[t + 512], b3 = s4[t + 768];
    float mnt = fminf(fminf(fminf(a0.x, a0.y), fminf(a0.z, a0.w)),
                      fminf(fminf(a1.x, a1.y), fminf(a1.z, a1.w)));
    mnt = fminf(mnt, fminf(fminf(fminf(a2.x, a2.y), fminf(a2.z, a2.w)),
                           fminf(fminf(a3.x, a3.y), fminf(a3.z, a3.w))));
    float mxt = fmaxf(fmaxf(fmaxf(a0.x, a0.y), fmaxf(a0.z, a0.w)),
                      fmaxf(fmaxf(a1.x, a1.y), fmaxf(a1.z, a1.w)));
    mxt = fmaxf(mxt, fmaxf(fmaxf(fmaxf(a2.x, a2.y), fmaxf(a2.z, a2.w)),
                           fmaxf(fmaxf(a3.x, a3.y), fmaxf(a3.z, a3.w))));
    float mns = fminf(fminf(fminf(b0.x, b0.y), fminf(b0.z, b0.w)),
                      fminf(fminf(b1.x, b1.y), fminf(b1.z, b1.w)));
    mns = fminf(mns, fminf(fminf(fminf(b2.x, b2.y), fminf(b2.z, b2.w)),
                           fminf(fminf(b3.x, b3.y), fminf(b3.z, b3.w))));
    float mxs = fmaxf(fmaxf(fmaxf(b0.x, b0.y), fmaxf(b0.z, b0.w)),
                      fmaxf(fmaxf(b1.x, b1.y), fmaxf(b1.z, b1.w)));
    mxs = fmaxf(mxs, fmaxf(fmaxf(fmaxf(b2.x, b2.y), fmaxf(b2.z, b2.w)),
                           fmaxf(fmaxf(b3.x, b3.y), fmaxf(b3.z, b3.w))));
    #pragma unroll
    for (int o = 32; o; o >>= 1) {
        mnt = fminf(mnt, __shfl_xor(mnt, o));
        mxt = fmaxf(mxt, __shfl_xor(mxt, o));
        mns = fminf(mns, __shfl_xor(mns, o));
        mxs = fmaxf(mxs, __shfl_xor(mxs, o));
    }
    int lane = t & 63, wave = t >> 6;
    if (lane == 0) sred[wave] = make_float4(mnt, mxt, mns, mxs);
    __syncthreads();
    if (t == 0) {
        float4 v0 = sred[0], v1 = sred[1], v2 = sred[2], v3 = sred[3];
        float4 r;
        r.x = fminf(fminf(v0.x, v1.x), fminf(v2.x, v3.x));
        r.y = fmaxf(fmaxf(v0.y, v1.y), fmaxf(v2.y, v3.y));
        r.z = fminf(fminf(v0.z, v1.z), fminf(v2.z, v3.z));
        r.w = fmaxf(fmaxf(v0.w, v1.w), fmaxf(v2.w, v3.w));
        pw[n * MM_BPS + j] = r;
    }
    int bid = n * MM_BPS + j;
    if (bid < 128) histall[bid * 256 + t] = 0.0f;    // zero NCOPY*4*1024 floats
}

// ---------------- dispatch 2: MFMA joint histogram ----------------
// A-frag: lane (g=lane>>5, c=lane&31) supplies A[c][8g+j], B[8g+j][c], j=0..7.
// C/D: col = lane&31, row = (reg&3) + 8*(reg>>2) + 4*g.  (validated R3..R7, absmax 0)

__device__ __forceinline__ void mfma_step(float4 xa, float4 xc, float4 ya, float4 yc,
                                          float q, float16& acc) {
    float xs[8] = {xa.x, xa.y, xa.z, xa.w, xc.x, xc.y, xc.z, xc.w};
    float ys[8] = {ya.x, ya.y, ya.z, ya.w, yc.x, yc.y, yc.z, yc.w};
    unsigned av[8], bv[8];
    #pragma unroll
    for (int jj = 0; jj < 8; jj++) {
        float d = xs[jj] - q;
        float arg = -d * d;
        float w;
        asm("v_exp_f32 %0, %1" : "=v"(w) : "v"(arg));
        av[jj] = __float_as_uint(w);
        d = ys[jj] - q;
        arg = -d * d;
        asm("v_exp_f32 %0, %1" : "=v"(w) : "v"(arg));
        bv[jj] = __float_as_uint(w);
    }
    union { unsigned u[4]; short8 v; } af, bf;
    #pragma unroll
    for (int jj = 0; jj < 4; jj++) {                // pack hi16 (bf16 trunc) pairs
        af.u[jj] = __builtin_amdgcn_perm(av[2 * jj + 1], av[2 * jj], 0x07060302u);
        bf.u[jj] = __builtin_amdgcn_perm(bv[2 * jj + 1], bv[2 * jj], 0x07060302u);
    }
    acc = __builtin_amdgcn_mfma_f32_32x32x16_bf16(af.v, bf.v, acc, 0, 0, 0);
}

__global__ void __launch_bounds__(256, 8)
k_hist(const float* __restrict__ tar, const float* __restrict__ src,
       const float4* __restrict__ pw, float* __restrict__ histall) {
    __shared__ __align__(16) float lds[4096];        // coords: 2*1728 used; merge: 4096
    __shared__ float4 sred[4];
    __shared__ float bc[4];
    int n = blockIdx.y, j = blockIdx.x;
    int t = threadIdx.x;

    // issue the big input loads first; they retire while we reduce partials
    const float4* t4 = (const float4*)(tar + (size_t)n * P_ELEMS) + (size_t)j * H_T4;
    const float4* s4 = (const float4*)(src + (size_t)n * P_ELEMS) + (size_t)j * H_T4;
    float4 a0 = t4[t];
    float4 b0 = s4[t];
    float4 a1 = make_float4(0.f, 0.f, 0.f, 0.f), b1 = a1;
    if (t < H_T4 - 256) { a1 = t4[t + 256]; b1 = s4[t + 256]; }

    // reduce the sample's 216 minmax partials (L2-hot)
    {
        const float4* pwn = pw + n * MM_BPS;
        float mnt = INFINITY, mxt = -INFINITY, mns = INFINITY, mxs = -INFINITY;
        if (t < MM_BPS) {
            float4 v = pwn[t];
            mnt = v.x; mxt = v.y; mns = v.z; mxs = v.w;
        }
        #pragma unroll
        for (int o = 32; o; o >>= 1) {
            mnt = fminf(mnt, __shfl_xor(mnt, o));
            mxt = fmaxf(mxt, __shfl_xor(mxt, o));
            mns = fminf(mns, __shfl_xor(mns, o));
            mxs = fmaxf(mxs, __shfl_xor(mxs, o));
        }
        int lane = t & 63, wave = t >> 6;
        if (lane == 0) sred[wave] = make_float4(mnt, mxt, mns, mxs);
        __syncthreads();
        if (t == 0) {
            float4 v0 = sred[0], v1 = sred[1], v2 = sred[2], v3 = sred[3];
            bc[0] = fminf(fminf(v0.x, v1.x), fminf(v2.x, v3.x));
            bc[1] = fmaxf(fmaxf(v0.y, v1.y), fmaxf(v2.y, v3.y));
            bc[2] = fminf(fminf(v0.z, v1.z), fminf(v2.z, v3.z));
            bc[3] = fmaxf(fmaxf(v0.w, v1.w), fmaxf(v2.w, v3.w));
        }
        __syncthreads();
    }
    float mnt = bc[0], mns = bc[2];
    float fit = 31.0f * WS / (bc[1] - mnt + 1e-12f);
    float fis = 31.0f * WS / (bc[3] - mns + 1e-12f);

    // stage pre-scaled bin coords: xb at lds[0..1727], yb at lds[1728..3455]
    {
        float4 xo, yo;
        xo.x = (a0.x - mnt) * fit; xo.y = (a0.y - mnt) * fit;
        xo.z = (a0.z - mnt) * fit; xo.w = (a0.w - mnt) * fit;
        ((float4*)lds)[t] = xo;
        yo.x = (b0.x - mns) * fis; yo.y = (b0.y - mns) * fis;
        yo.z = (b0.z - mns) * fis; yo.w = (b0.w - mns) * fis;
        ((float4*)(lds + H_TILE))[t] = yo;
        if (t < H_T4 - 256) {
            xo.x = (a1.x - mnt) * fit; xo.y = (a1.y - mnt) * fit;
            xo.z = (a1.z - mnt) * fit; xo.w = (a1.w - mnt) * fit;
            ((float4*)lds)[t + 256] = xo;
            yo.x = (b1.x - mns) * fis; yo.y = (b1.y - mns) * fis;
            yo.z = (b1.z - mns) * fis; yo.w = (b1.w - mns) * fis;
            ((float4*)(lds + H_TILE))[t + 256] = yo;
        }
    }
    __syncthreads();

    int lane = t & 63, wave = t >> 6, g = lane >> 5;
    float q = (float)(lane & 31) * WS;
    const float* xb = lds + wave * WSLICE;
    const float* yb = lds + H_TILE + wave * WSLICE;

    float16 acc;
    #pragma unroll
    for (int i = 0; i < 16; i++) acc[i] = 0.0f;

    // software-pipelined: prefetch iter it+1's LDS reads before computing iter it
    int kb = g * 8;
    float4 xa = *(const float4*)(xb + kb);
    float4 xc = *(const float4*)(xb + kb + 4);
    float4 ya = *(const float4*)(yb + kb);
    float4 yc = *(const float4*)(yb + kb + 4);
    #pragma unroll 3
    for (int it = 0; it < NITER - 1; it++) {
        int nk = (it + 1) * 16 + g * 8;
        float4 nxa = *(const float4*)(xb + nk);
        float4 nxc = *(const float4*)(xb + nk + 4);
        float4 nya = *(const float4*)(yb + nk);
        float4 nyc = *(const float4*)(yb + nk + 4);
        mfma_step(xa, xc, ya, yc, q, acc);
        xa = nxa; xc = nxc; ya = nya; yc = nyc;
    }
    mfma_step(xa, xc, ya, yc, q, acc);

    __syncthreads();
    {
        float* hw = lds + wave * 1024;
        int col = lane & 31;
        #pragma unroll
        for (int reg = 0; reg < 16; reg++) {
            int row = (reg & 3) + 8 * (reg >> 2) + 4 * g;
            hw[row * 32 + col] = acc[reg];
        }
    }
    __syncthreads();
    // merge into one of NCOPY replicated hists (spread over XCD round-robin)
    float* histn = histall + ((j & (NCOPY - 1)) * N_SAMPLES + n) * 1024;
    for (int bb = t; bb < 1024; bb += 256) {
        float v = lds[bb] + lds[1024 + bb] + lds[2048 + bb] + lds[3072 + bb];
        unsafeAtomicAdd(&histn[bb], v);
    }
}

// ---------------- dispatch 3: entropies + loss ----------------

__global__ void __launch_bounds__(256)
k_final(const float* __restrict__ histall, float* __restrict__ out) {
    __shared__ float sh[4096];
    __shared__ float wres[4];
    int t = threadIdx.x;
    int lane = t & 63, nn = t >> 6;
    float4 h[4];
    float part = 0.0f;
    #pragma unroll
    for (int r = 0; r < 4; r++) {
        float4 s = make_float4(0.f, 0.f, 0.f, 0.f);
        #pragma unroll
        for (int c = 0; c < NCOPY; c++) {
            const float4* h4 = (const float4*)(histall + (c * N_SAMPLES + nn) * 1024);
            float4 v = h4[lane * 4 + r];
            s.x += v.x; s.y += v.y; s.z += v.z; s.w += v.w;
        }
        h[r] = s;
        part += (s.x + s.y) + (s.z + s.w);
    }
    #pragma unroll
    for (int o = 32; o; o >>= 1) part += __shfl_xor(part, o);
    float inv = 1.0f / part;
    float ej = 0.0f;
    #pragma unroll
    for (int r = 0; r < 4; r++) {
        float4 p;
        p.x = h[r].x * inv; p.y = h[r].y * inv; p.z = h[r].z * inv; p.w = h[r].w * inv;
        ((float4*)(sh + nn * 1024))[lane * 4 + r] = p;
        ej -= p.x * __logf(p.x + EPSR) + p.y * __logf(p.y + EPSR)
            + p.z * __logf(p.z + EPSR) + p.w * __logf(p.w + EPSR);
    }
    #pragma unroll
    for (int o = 32; o; o >>= 1) ej += __shfl_xor(ej, o);
    __syncthreads();
    float m = 0.0f;
    if (lane < 32) {
        int row = lane;
        for (int jj = 0; jj < 32; jj++) m += sh[nn * 1024 + row * 32 + ((jj + row) & 31)];
    } else {
        int col = lane - 32;
        for (int i = 0; i < 32; i++) m += sh[nn * 1024 + i * 32 + col];
    }
    float rc = -m * __logf(m + EPSR);
    #pragma unroll
    for (int o = 16; o; o >>= 1) rc += __shfl_xor(rc, o);   // halves reduce separately
    float es = __shfl(rc, 32);
    if (lane == 0) wres[nn] = (rc + es) / ej;
    __syncthreads();
    if (t == 0)
        out[0] = -(wres[0] + wres[1] + wres[2] + wres[3]) * 0.25f;
}

extern "C" void kernel_launch(void* const* d_in, const int* in_sizes, int n_in,
                              void* d_out, int out_size, void* d_ws, size_t ws_size,
                              hipStream_t stream) {
    const float* tar = (const float*)d_in[0];
    const float* src = (const float*)d_in[1];
    float* out = (float*)d_out;
    float4* pw = (float4*)d_ws;                                  // 864 slots used
    float* histall = (float*)((char*)d_ws + PW_SLOTS * 16);      // NCOPY*4*1024 floats

    k_minmax<<<dim3(MM_BPS, N_SAMPLES), 256, 0, stream>>>(tar, src, pw, histall);
    k_hist<<<dim3(H_BPS, N_SAMPLES), 256, 0, stream>>>(tar, src, pw, histall);
    k_final<<<1, 256, 0, stream>>>(histall, out);
}

// Round 9
// 111.757 us; speedup vs baseline: 1.0053x; 1.0053x over previous
//
#include <hip/hip_runtime.h>
#include <math.h>

#define N_SAMPLES 4
#define P_ELEMS   (96*96*96)          // 884736
// minmax geometry: deep loads, pure BW
#define MM_BPS    216
#define MM_T4     1024                // float4 per array per block (4/thread)
// hist geometry: 1728 blocks, 2048 elements/block, 512/wave = 16 k-groups of 32
#define H_BPS     432
#define H_TILE    2048
#define H_T4      (H_TILE/4)          // 512 float4 per array per block
#define NCOPY     8                   // replicated global hists (contention / XCD spread)
#define PW_SLOTS  1728                // ws layout constant (matches prior rounds)
// weight = exp(-(xb-k)^2 * 2048/961) = exp2(-((xb-k)*WS)^2), WS = sqrt(2048/961*log2 e)
#define WS        1.75343855f
#define EPSR      1e-10f

typedef __attribute__((ext_vector_type(8)))  short short8;
typedef __attribute__((ext_vector_type(4)))  float floatx4;

// ---------------- dispatch 1: per-block minmax partials + hist zeroing ----------------

__global__ void __launch_bounds__(256)
k_minmax(const float* __restrict__ tar, const float* __restrict__ src,
         float4* __restrict__ pw, float* __restrict__ histall) {
    __shared__ float4 sred[4];
    int n = blockIdx.y, j = blockIdx.x;
    int t = threadIdx.x;
    const float4* t4 = (const float4*)(tar + (size_t)n * P_ELEMS) + (size_t)j * MM_T4;
    const float4* s4 = (const float4*)(src + (size_t)n * P_ELEMS) + (size_t)j * MM_T4;
    float4 a0 = t4[t], a1 = t4[t + 256], a2 = t4[t + 512], a3 = t4[t + 768];
    float4 b0 = s4[t], b1 = s4[t + 256], b2 = s4[t + 512], b3 = s4[t + 768];
    float mnt = fminf(fminf(fminf(a0.x, a0.y), fminf(a0.z, a0.w)),
                      fminf(fminf(a1.x, a1.y), fminf(a1.z, a1.w)));
    mnt = fminf(mnt, fminf(fminf(fminf(a2.x, a2.y), fminf(a2.z, a2.w)),
                           fminf(fminf(a3.x, a3.y), fminf(a3.z, a3.w))));
    float mxt = fmaxf(fmaxf(fmaxf(a0.x, a0.y), fmaxf(a0.z, a0.w)),
                      fmaxf(fmaxf(a1.x, a1.y), fmaxf(a1.z, a1.w)));
    mxt = fmaxf(mxt, fmaxf(fmaxf(fmaxf(a2.x, a2.y), fmaxf(a2.z, a2.w)),
                           fmaxf(fmaxf(a3.x, a3.y), fmaxf(a3.z, a3.w))));
    float mns = fminf(fminf(fminf(b0.x, b0.y), fminf(b0.z, b0.w)),
                      fminf(fminf(b1.x, b1.y), fminf(b1.z, b1.w)));
    mns = fminf(mns, fminf(fminf(fminf(b2.x, b2.y), fminf(b2.z, b2.w)),
                           fminf(fminf(b3.x, b3.y), fminf(b3.z, b3.w))));
    float mxs = fmaxf(fmaxf(fmaxf(b0.x, b0.y), fmaxf(b0.z, b0.w)),
                      fmaxf(fmaxf(b1.x, b1.y), fmaxf(b1.z, b1.w)));
    mxs = fmaxf(mxs, fmaxf(fmaxf(fmaxf(b2.x, b2.y), fmaxf(b2.z, b2.w)),
                           fmaxf(fmaxf(b3.x, b3.y), fmaxf(b3.z, b3.w))));
    #pragma unroll
    for (int o = 32; o; o >>= 1) {
        mnt = fminf(mnt, __shfl_xor(mnt, o));
        mxt = fmaxf(mxt, __shfl_xor(mxt, o));
        mns = fminf(mns, __shfl_xor(mns, o));
        mxs = fmaxf(mxs, __shfl_xor(mxs, o));
    }
    int lane = t & 63, wave = t >> 6;
    if (lane == 0) sred[wave] = make_float4(mnt, mxt, mns, mxs);
    __syncthreads();
    if (t == 0) {
        float4 v0 = sred[0], v1 = sred[1], v2 = sred[2], v3 = sred[3];
        float4 r;
        r.x = fminf(fminf(v0.x, v1.x), fminf(v2.x, v3.x));
        r.y = fmaxf(fmaxf(v0.y, v1.y), fmaxf(v2.y, v3.y));
        r.z = fminf(fminf(v0.z, v1.z), fminf(v2.z, v3.z));
        r.w = fmaxf(fmaxf(v0.w, v1.w), fmaxf(v2.w, v3.w));
        pw[n * MM_BPS + j] = r;
    }
    int bid = n * MM_BPS + j;
    if (bid < 128) histall[bid * 256 + t] = 0.0f;    // zero NCOPY*4*1024 floats
}

// ---------------- dispatch 2: MFMA joint histogram, 16x16x32 x 4 bin-tiles ----------------
// A-frag (16x16x32): lane supplies A[m=lane&15][k=(lane>>4)*8+j], j=0..7 (m120, HW-verified).
// B-frag mirrored: B[k=(lane>>4)*8+j][n=lane&15].
// C/D: col=lane&15, row=(lane>>4)*4+reg (m89, HW-verified).
// 4 MFMAs per 32 elements cover the 32x32 bin grid as 16x16 quadrants.

__device__ __forceinline__ void wpack8(const float s[8], float c, unsigned out[4]) {
    unsigned w[8];
    #pragma unroll
    for (int jj = 0; jj < 8; jj++) {
        float d = s[jj] - c;
        float arg = -d * d;
        float e;
        asm("v_exp_f32 %0, %1" : "=v"(e) : "v"(arg));
        w[jj] = __float_as_uint(e);
    }
    #pragma unroll
    for (int p = 0; p < 4; p++)      // pack hi16 (bf16 trunc) pairs
        out[p] = __builtin_amdgcn_perm(w[2 * p + 1], w[2 * p], 0x07060302u);
}

__global__ void __launch_bounds__(256, 6)
k_hist(const float* __restrict__ tar, const float* __restrict__ src,
       const float4* __restrict__ pw, float* __restrict__ histall) {
    __shared__ __align__(16) float lds[4096];        // coords 2*2048; reused for merge
    __shared__ float4 sred[4];
    __shared__ float bc[4];
    int n = blockIdx.y, j = blockIdx.x;
    int t = threadIdx.x;

    // issue the big input loads first; they retire while we reduce partials
    const float4* t4 = (const float4*)(tar + (size_t)n * P_ELEMS) + (size_t)j * H_T4;
    const float4* s4 = (const float4*)(src + (size_t)n * P_ELEMS) + (size_t)j * H_T4;
    float4 a0 = t4[t], a1 = t4[t + 256];
    float4 b0 = s4[t], b1 = s4[t + 256];

    // reduce the sample's 216 minmax partials (L2-hot)
    {
        const float4* pwn = pw + n * MM_BPS;
        float mnt = INFINITY, mxt = -INFINITY, mns = INFINITY, mxs = -INFINITY;
        if (t < MM_BPS) {
            float4 v = pwn[t];
            mnt = v.x; mxt = v.y; mns = v.z; mxs = v.w;
        }
        #pragma unroll
        for (int o = 32; o; o >>= 1) {
            mnt = fminf(mnt, __shfl_xor(mnt, o));
            mxt = fmaxf(mxt, __shfl_xor(mxt, o));
            mns = fminf(mns, __shfl_xor(mns, o));
            mxs = fmaxf(mxs, __shfl_xor(mxs, o));
        }
        int lane = t & 63, wave = t >> 6;
        if (lane == 0) sred[wave] = make_float4(mnt, mxt, mns, mxs);
        __syncthreads();
        if (t == 0) {
            float4 v0 = sred[0], v1 = sred[1], v2 = sred[2], v3 = sred[3];
            bc[0] = fminf(fminf(v0.x, v1.x), fminf(v2.x, v3.x));
            bc[1] = fmaxf(fmaxf(v0.y, v1.y), fmaxf(v2.y, v3.y));
            bc[2] = fminf(fminf(v0.z, v1.z), fminf(v2.z, v3.z));
            bc[3] = fmaxf(fmaxf(v0.w, v1.w), fmaxf(v2.w, v3.w));
        }
        __syncthreads();
    }
    float mnt = bc[0], mns = bc[2];
    float fit = 31.0f * WS / (bc[1] - mnt + 1e-12f);
    float fis = 31.0f * WS / (bc[3] - mns + 1e-12f);

    // stage pre-scaled bin coords: x at lds[0..2047], y at lds[2048..4095]
    {
        float4 xo, yo;
        xo.x = (a0.x - mnt) * fit; xo.y = (a0.y - mnt) * fit;
        xo.z = (a0.z - mnt) * fit; xo.w = (a0.w - mnt) * fit;
        ((float4*)lds)[t] = xo;
        xo.x = (a1.x - mnt) * fit; xo.y = (a1.y - mnt) * fit;
        xo.z = (a1.z - mnt) * fit; xo.w = (a1.w - mnt) * fit;
        ((float4*)lds)[t + 256] = xo;
        yo.x = (b0.x - mns) * fis; yo.y = (b0.y - mns) * fis;
        yo.z = (b0.z - mns) * fis; yo.w = (b0.w - mns) * fis;
        ((float4*)(lds + H_TILE))[t] = yo;
        yo.x = (b1.x - mns) * fis; yo.y = (b1.y - mns) * fis;
        yo.z = (b1.z - mns) * fis; yo.w = (b1.w - mns) * fis;
        ((float4*)(lds + H_TILE))[t + 256] = yo;
    }
    __syncthreads();

    int lane = t & 63, wave = t >> 6, quad = lane >> 4;
    float c0 = (float)(lane & 15) * WS;              // bins m and m+16, pre-scaled
    float c1 = c0 + 16.0f * WS;
    const float* xb = lds + wave * 512;              // 512 elements per wave
    const float* yb = lds + H_TILE + wave * 512;

    floatx4 acc00, acc01, acc10, acc11;
    #pragma unroll
    for (int i = 0; i < 4; i++) { acc00[i] = 0.f; acc01[i] = 0.f; acc10[i] = 0.f; acc11[i] = 0.f; }

    #pragma unroll 2
    for (int it = 0; it < 16; it++) {                // 32 elements per iteration
        int kb = it * 32 + quad * 8;
        float4 xa = *(const float4*)(xb + kb);
        float4 xc = *(const float4*)(xb + kb + 4);
        float4 ya = *(const float4*)(yb + kb);
        float4 yc = *(const float4*)(yb + kb + 4);
        float xs[8] = {xa.x, xa.y, xa.z, xa.w, xc.x, xc.y, xc.z, xc.w};
        float ys[8] = {ya.x, ya.y, ya.z, ya.w, yc.x, yc.y, yc.z, yc.w};
        union { unsigned u[4]; short8 v; } A0, A1, B0, B1;
        wpack8(xs, c0, A0.u);
        wpack8(xs, c1, A1.u);
        wpack8(ys, c0, B0.u);
        wpack8(ys, c1, B1.u);
        acc00 = __builtin_amdgcn_mfma_f32_16x16x32_bf16(A0.v, B0.v, acc00, 0, 0, 0);
        acc01 = __builtin_amdgcn_mfma_f32_16x16x32_bf16(A0.v, B1.v, acc01, 0, 0, 0);
        acc10 = __builtin_amdgcn_mfma_f32_16x16x32_bf16(A1.v, B0.v, acc10, 0, 0, 0);
        acc11 = __builtin_amdgcn_mfma_f32_16x16x32_bf16(A1.v, B1.v, acc11, 0, 0, 0);
    }

    __syncthreads();
    {
        // hw[xbin*32 + ybin]; D row = x-bin (+16I), col = y-bin (+16J)
        float* hw = lds + wave * 1024;
        int col = lane & 15;
        int rbase = quad * 4;
        #pragma unroll
        for (int reg = 0; reg < 4; reg++) {
            hw[(rbase + reg) * 32 + col]             = acc00[reg];
            hw[(rbase + reg) * 32 + col + 16]        = acc01[reg];
            hw[(rbase + reg + 16) * 32 + col]        = acc10[reg];
            hw[(rbase + reg + 16) * 32 + col + 16]   = acc11[reg];
        }
    }
    __syncthreads();
    // merge into one of NCOPY replicated hists (spread over XCD round-robin)
    float* histn = histall + ((j & (NCOPY - 1)) * N_SAMPLES + n) * 1024;
    for (int bb = t; bb < 1024; bb += 256) {
        float v = lds[bb] + lds[1024 + bb] + lds[2048 + bb] + lds[3072 + bb];
        unsafeAtomicAdd(&histn[bb], v);
    }
}

// ---------------- dispatch 3: entropies + loss ----------------

__global__ void __launch_bounds__(256)
k_final(const float* __restrict__ histall, float* __restrict__ out) {
    __shared__ float sh[4096];
    __shared__ float wres[4];
    int t = threadIdx.x;
    int lane = t & 63, nn = t >> 6;
    float4 h[4];
    float part = 0.0f;
    #pragma unroll
    for (int r = 0; r < 4; r++) {
        float4 s = make_float4(0.f, 0.f, 0.f, 0.f);
        #pragma unroll
        for (int c = 0; c < NCOPY; c++) {
            const float4* h4 = (const float4*)(histall + (c * N_SAMPLES + nn) * 1024);
            float4 v = h4[lane * 4 + r];
            s.x += v.x; s.y += v.y; s.z += v.z; s.w += v.w;
        }
        h[r] = s;
        part += (s.x + s.y) + (s.z + s.w);
    }
    #pragma unroll
    for (int o = 32; o; o >>= 1) part += __shfl_xor(part, o);
    float inv = 1.0f / part;
    float ej = 0.0f;
    #pragma unroll
    for (int r = 0; r < 4; r++) {
        float4 p;
        p.x = h[r].x * inv; p.y = h[r].y * inv; p.z = h[r].z * inv; p.w = h[r].w * inv;
        ((float4*)(sh + nn * 1024))[lane * 4 + r] = p;
        ej -= p.x * __logf(p.x + EPSR) + p.y * __logf(p.y + EPSR)
            + p.z * __logf(p.z + EPSR) + p.w * __logf(p.w + EPSR);
    }
    #pragma unroll
    for (int o = 32; o; o >>= 1) ej += __shfl_xor(ej, o);
    __syncthreads();
    float m = 0.0f;
    if (lane < 32) {
        int row = lane;
        for (int jj = 0; jj < 32; jj++) m += sh[nn * 1024 + row * 32 + ((jj + row) & 31)];
    } else {
        int col = lane - 32;
        for (int i = 0; i < 32; i++) m += sh[nn * 1024 + i * 32 + col];
    }
    float rc = -m * __logf(m + EPSR);
    #pragma unroll
    for (int o = 16; o; o >>= 1) rc += __shfl_xor(rc, o);   // halves reduce separately
    float es = __shfl(rc, 32);
    if (lane == 0) wres[nn] = (rc + es) / ej;
    __syncthreads();
    if (t == 0)
        out[0] = -(wres[0] + wres[1] + wres[2] + wres[3]) * 0.25f;
}

extern "C" void kernel_launch(void* const* d_in, const int* in_sizes, int n_in,
                              void* d_out, int out_size, void* d_ws, size_t ws_size,
                              hipStream_t stream) {
    const float* tar = (const float*)d_in[0];
    const float* src = (const float*)d_in[1];
    float* out = (float*)d_out;
    float4* pw = (float4*)d_ws;                                  // 864 slots used
    float* histall = (float*)((char*)d_ws + PW_SLOTS * 16);      // NCOPY*4*1024 floats

    k_minmax<<<dim3(MM_BPS, N_SAMPLES), 256, 0, stream>>>(tar, src, pw, histall);
    k_hist<<<dim3(H_BPS, N_SAMPLES), 256, 0, stream>>>(tar, src, pw, histall);
    k_final<<<1, 256, 0, stream>>>(histall, out);
}